// Round 10
// baseline (222.515 us; speedup 1.0000x reference)
//
#include <hip/hip_runtime.h>
#include <math.h>

typedef _Float16 half8  __attribute__((ext_vector_type(8)));
typedef float    float4v __attribute__((ext_vector_type(4)));

constexpr int T_ = 1 << 18;            // hash table size per level
constexpr unsigned TMASK = T_ - 1;
constexpr unsigned PRIME = 2654435761u;

// ws layout:
//   [0, 22528)      : 22 W-fragments (f16), frag f: 64 lanes x 8 halfs
//   [22528, 23360)  : biases fp32: b1[64] b2[64] b3[64] b4[16]
//   [23360, 23424)  : N_values fp32 [16]
//   [23424, 23488)  : level offsets fp32 [16] (prefix sum of N_l+1)
//   [23488, 57280)  : packed v1/v2 table, f16x4 per entry: {v1.x,v1.y,v2.x,v2.y}
constexpr int WFRAG_HALFS = 22 * 64 * 8;   // 11264 halfs = 22528 B
constexpr int BIAS_FLOATS = 208;           // 3*64 + 16
constexpr int WS_BYTES    = 22528 + 240 * 4;   // 23488 (LDS-resident part)
constexpr int WS_UINT4    = WS_BYTES / 16;     // 1468
constexpr int V12_OFF     = 23488;         // byte offset of packed v12 in ws

// R10: zero-shuffle layer handoff. The inter-layer LDS round-trips (write ->
// lgkmcnt(0) -> read, ~250-300cy x3 per tile) were the serial wall (time was
// invariant to occupancy/fences/pipelining; only the MLP chain remains).
// Fix: re-swizzle the W2/W3/W4 k-positions at prep so each lane's next-layer
// B-operand values are EXACTLY its own MFMA D outputs: sigma_s(8g+4u+r) =
// 32s+16u+4g+r. Handoff = 16 in-register f32->f16 converts (same casts as
// before -> bit-exact). sH/DS_FENCE/H-bank-conflicts deleted. Gather pipeline
// deepened to 2 tiles (MLP is now shorter than v3's L3 latency).
constexpr int BLK   = 256;                 // threads / block (4 waves)
constexpr int PTS_PER_BLOCK = 512;         // 4 waves x 8 tiles x 16 pts

struct Meta { float n[16]; float off[16]; };

// ---------------- prep: swizzle weights + pack v12 table ----------------
__global__ void prep_weights(const float* __restrict__ W1, const float* __restrict__ b1,
                             const float* __restrict__ W2, const float* __restrict__ b2,
                             const float* __restrict__ W3, const float* __restrict__ b3,
                             const float* __restrict__ W4, const float* __restrict__ b4,
                             const float2* __restrict__ table,
                             _Float16* __restrict__ wsW, float* __restrict__ wsB,
                             uint2* __restrict__ wsV, Meta mv)
{
    const int tid = threadIdx.x;
    const int bid = blockIdx.x;
    if (bid < 44) {
        const int e = bid * 256 + tid;              // 44*256 == WFRAG_HALFS exactly
        const int frag = e >> 9;
        const int l    = (e >> 3) & 63;
        const int j    = e & 7;
        const int g = l >> 4, m = l & 15;
        const int u = j >> 2, r = j & 3;            // k-pos split for sigma swizzle
        float v;
        if (frag < 4) {                       // L1: W1 (32x64), identity k-map
            v = W1[(8*g + j) * 64 + 16*frag + m];
        } else if (frag < 12) {               // L2: rows = sigma_s(8g+j) = 32s+16u+4g+r
            const int s = (frag - 4) >> 2, t = (frag - 4) & 3;
            v = W2[(32*s + 16*u + 4*g + r) * 64 + 16*t + m];
        } else if (frag < 20) {               // L3: ditto
            const int s = (frag - 12) >> 2, t = (frag - 12) & 3;
            v = W3[(32*s + 16*u + 4*g + r) * 64 + 16*t + m];
        } else {                              // L4 (64x3): ditto, pad n>=3 with 0
            const int s = frag - 20;
            v = (m < 3) ? W4[(32*s + 16*u + 4*g + r) * 3 + m] : 0.f;
        }
        wsW[e] = (_Float16)v;
    } else if (bid == 44) {
        if (tid < 64) { wsB[tid] = b1[tid]; wsB[64 + tid] = b2[tid]; wsB[128 + tid] = b3[tid]; }
        else if (tid < 80)  { const int r2 = tid - 64; wsB[192 + r2] = (r2 < 3) ? b4[r2] : 0.f; }
        else if (tid < 96)  wsB[BIAS_FLOATS + (tid - 80)] = mv.n[tid - 80];
        else if (tid < 112) wsB[BIAS_FLOATS + 16 + (tid - 96)] = mv.off[tid - 96];
    } else {
        // packed v12 table: entry e -> (level l, index i)
        const int e = (bid - 45) * 256 + tid;
        const int total = (int)mv.off[15] + (int)mv.n[15] + 1;   // 4194
        if (e < total) {
            int l = 0;
            #pragma unroll
            for (int k = 1; k < 16; ++k) if (e >= (int)mv.off[k]) l = k;
            const int i = e - (int)mv.off[l];
            const float2* tl = table + (size_t)l * T_;
            const float2 b = tl[((unsigned)i * PRIME) & TMASK];  // v1 source
            const float2 a = tl[i];                              // v2 source
            union { _Float16 h[2]; unsigned u; } p0, p1;
            p0.h[0] = (_Float16)b.x; p0.h[1] = (_Float16)b.y;
            p1.h[0] = (_Float16)a.x; p1.h[1] = (_Float16)a.y;
            wsV[e] = uint2{p0.u, p1.u};
        }
    }
}

// ---------------- main fused kernel ----------------
struct Gather {                // pipeline state: v3 f32 + v1/v2 packed f16 (16 regs)
    float2   v3[4];
    unsigned v1[4];
    unsigned v2[4];
};

__device__ __forceinline__ void issue_gather(Gather& G, const float2 xy,
                                             const float2* __restrict__ table,
                                             const unsigned* __restrict__ gV12,
                                             const float (&nvq)[4], const int (&offq)[4],
                                             const int g)
{
    #pragma unroll
    for (int q = 0; q < 4; ++q) {
        const float n = nvq[q];
        const float xs = xy.x * n, ys = xy.y * n;
        const int xi = (int)floorf(xs);
        const int yi = (int)floorf(ys);
        const unsigned yp = (unsigned)yi * PRIME;
        G.v3[q] = table[(size_t)(4*g + q) * T_ + (((unsigned)xi ^ yp) & TMASK)];
        G.v1[q] = gV12[2*(offq[q] + yi) + 0];
        G.v2[q] = gV12[2*(offq[q] + xi) + 1];
    }
}

__device__ __forceinline__ half8 make_feat(const float2 xy, const Gather& G,
                                           const float (&nvq)[4],
                                           const float2 (&v0c)[4])
{
    half8 feat;
    #pragma unroll
    for (int q = 0; q < 4; ++q) {
        const float n = nvq[q];
        const float xs = xy.x * n, ys = xy.y * n;
        const float xf = floorf(xs), yf = floorf(ys);
        const float fx = xs - xf, fy = ys - yf;
        union { unsigned u; _Float16 h[2]; } u1, u2;
        u1.u = G.v1[q]; u2.u = G.v2[q];
        const float cx = 1.f - fx, cy = 1.f - fy;
        const float w0 = cx*cy, w1 = cx*fy, w2 = fx*cy, w3 = fx*fy;
        feat[2*q+0] = (_Float16)(w0*v0c[q].x + w1*(float)u1.h[0] + w2*(float)u2.h[0] + w3*G.v3[q].x);
        feat[2*q+1] = (_Float16)(w0*v0c[q].y + w1*(float)u1.h[1] + w2*(float)u2.h[1] + w3*G.v3[q].y);
    }
    return feat;
}

// in-register layer handoff: leaky-relu + f16, a_s[4u+r] = f16(leaky(acc[2s+u][r]))
__device__ __forceinline__ void repack(const float4v (&acc)[4], half8& a0, half8& a1)
{
    #pragma unroll
    for (int u = 0; u < 2; ++u)
        #pragma unroll
        for (int r = 0; r < 4; ++r) {
            const float v0 = acc[u][r];
            const float v1 = acc[2 + u][r];
            a0[4*u + r] = (_Float16)(v0 > 0.f ? v0 : 0.01f * v0);
            a1[4*u + r] = (_Float16)(v1 > 0.f ? v1 : 0.01f * v1);
        }
}

__global__ __launch_bounds__(BLK)
void fused_hashnerf_mfma(const float2* __restrict__ X,
                         const float2* __restrict__ table,
                         const uint4* __restrict__ ws,
                         float* __restrict__ out)
{
    __shared__ uint4 sRaw[WS_UINT4];           // W frags (f16) + biases + meta (23.5 KB)

    const int tid = threadIdx.x;
    for (int i = tid; i < WS_UINT4; i += BLK) sRaw[i] = ws[i];
    __syncthreads();

    const _Float16* Wl = (const _Float16*)sRaw;
    const float*    Bl = (const float*)(sRaw + (22528 / 16));
    const unsigned* gV12 = (const unsigned*)((const char*)ws + V12_OFF);

    const int wave = tid >> 6, lane = tid & 63;
    const int g = lane >> 4, c = lane & 15;

    // loop-invariant bias fragments: C'[n_out = 16t + 4g + r][pt]
    float4v b1f[4], b2f[4], b3f[4], b4f;
    #pragma unroll
    for (int t = 0; t < 4; ++t) {
        b1f[t] = *(const float4v*)(Bl +       16*t + 4*g);
        b2f[t] = *(const float4v*)(Bl +  64 + 16*t + 4*g);
        b3f[t] = *(const float4v*)(Bl + 128 + 16*t + 4*g);
    }
    b4f = *(const float4v*)(Bl + 192 + 4*g);
    float nvq[4];
    int   offq[4];
    #pragma unroll
    for (int q = 0; q < 4; ++q) {
        nvq[q]  = Bl[BIAS_FLOATS + 4*g + q];
        offq[q] = (int)Bl[BIAS_FLOATS + 16 + 4*g + q];
    }

    const int base_pt = blockIdx.x * PTS_PER_BLOCK + wave * 128;

    // X for all 8 tiles (coalesced/broadcast, static indices after unroll)
    float2 xy[8];
    #pragma unroll
    for (int it = 0; it < 8; ++it) xy[it] = X[base_pt + it*16 + c];

    // per-level constant corner (0,0): v0 = table[lv*T + 0] (f32, exact)
    float2 v0c[4];
    #pragma unroll
    for (int q = 0; q < 4; ++q) v0c[q] = table[(size_t)(4*g + q) * T_];

    // depth-2 gather pipeline: 3 rotating buffers, all indices static after unroll
    Gather G0, G1, G2;
    issue_gather(G0, xy[0], table, gV12, nvq, offq, g);
    issue_gather(G1, xy[1], table, gV12, nvq, offq, g);

    #pragma unroll
    for (int it = 0; it < 8; ++it) {
        Gather& Gc = (it % 3 == 0) ? G0 : (it % 3 == 1) ? G1 : G2;
        Gather& Gn = ((it + 2) % 3 == 0) ? G0 : ((it + 2) % 3 == 1) ? G1 : G2;

        // ---- consume tile it (vmcnt wait for its 12 loads; 12 newer stay in flight)
        const half8 feat = make_feat(xy[it], Gc, nvq, v0c);

        // ---- issue tile it+2's gathers ----
        if (it < 6) issue_gather(Gn, xy[it+2], table, gV12, nvq, offq, g);
        __builtin_amdgcn_sched_barrier(0);

        // ---- L1: 4 independent MFMAs ----
        float4v acc[4];
        #pragma unroll
        for (int t = 0; t < 4; ++t) {
            const half8 wf = *(const half8*)(Wl + (t*64 + lane)*8);
            acc[t] = __builtin_amdgcn_mfma_f32_16x16x32_f16(wf, feat, b1f[t], 0, 0, 0);
        }

        // ---- L2 (in-register handoff, sigma-swizzled weights) ----
        half8 a0, a1;
        repack(acc, a0, a1);
        #pragma unroll
        for (int t = 0; t < 4; ++t) {
            const half8 w0f = *(const half8*)(Wl + ((4 + t)*64 + lane)*8);
            const half8 w1f = *(const half8*)(Wl + ((8 + t)*64 + lane)*8);
            float4v a = __builtin_amdgcn_mfma_f32_16x16x32_f16(w0f, a0, b2f[t], 0, 0, 0);
            acc[t]    = __builtin_amdgcn_mfma_f32_16x16x32_f16(w1f, a1, a,      0, 0, 0);
        }

        // ---- L3 ----
        repack(acc, a0, a1);
        #pragma unroll
        for (int t = 0; t < 4; ++t) {
            const half8 w0f = *(const half8*)(Wl + ((12 + t)*64 + lane)*8);
            const half8 w1f = *(const half8*)(Wl + ((16 + t)*64 + lane)*8);
            float4v a = __builtin_amdgcn_mfma_f32_16x16x32_f16(w0f, a0, b3f[t], 0, 0, 0);
            acc[t]    = __builtin_amdgcn_mfma_f32_16x16x32_f16(w1f, a1, a,      0, 0, 0);
        }

        // ---- L4: n_out = 0..2 live in lanes g==0 ----
        repack(acc, a0, a1);
        const half8 w40 = *(const half8*)(Wl + (20*64 + lane)*8);
        const half8 w41 = *(const half8*)(Wl + (21*64 + lane)*8);
        float4v o = __builtin_amdgcn_mfma_f32_16x16x32_f16(w40, a0, b4f, 0, 0, 0);
        o         = __builtin_amdgcn_mfma_f32_16x16x32_f16(w41, a1, o,   0, 0, 0);
        if (g == 0) {
            float* op = out + (size_t)3 * (base_pt + it * 16 + c);
            op[0] = fmaxf(o[0], 0.f);
            op[1] = fmaxf(o[1], 0.f);
            op[2] = fmaxf(o[2], 0.f);
        }
    }
}

extern "C" void kernel_launch(void* const* d_in, const int* in_sizes, int n_in,
                              void* d_out, int out_size, void* d_ws, size_t ws_size,
                              hipStream_t stream) {
    const float2* X     = (const float2*)d_in[0];
    const float2* table = (const float2*)d_in[1];
    const float*  W1    = (const float*)d_in[2];
    const float*  b1    = (const float*)d_in[3];
    const float*  W2    = (const float*)d_in[4];
    const float*  b2    = (const float*)d_in[5];
    const float*  W3    = (const float*)d_in[6];
    const float*  b3    = (const float*)d_in[7];
    const float*  W4    = (const float*)d_in[8];
    const float*  b4    = (const float*)d_in[9];
    float* out          = (float*)d_out;

    const int npts = in_sizes[0] / 2;

    Meta mv;
    const double bg = exp((log(1024.0) - log(16.0)) / 15.0);
    int acc = 0;
    for (int l = 0; l < 16; ++l) {
        const float nl = floorf((float)(16.0 * pow(bg, (double)l)));
        mv.n[l]   = nl;
        mv.off[l] = (float)acc;
        acc += (int)nl + 1;
    }

    _Float16* wsW = (_Float16*)d_ws;
    float*    wsB = (float*)((char*)d_ws + 22528);
    uint2*    wsV = (uint2*)((char*)d_ws + V12_OFF);

    // 45 blocks: W frags + bias/meta; 17 blocks: packed v12 (4352 >= 4194 entries)
    prep_weights<<<62, 256, 0, stream>>>(W1, b1, W2, b2, W3, b3, W4, b4, table,
                                         wsW, wsB, wsV, mv);
    fused_hashnerf_mfma<<<npts / PTS_PER_BLOCK, BLK, 0, stream>>>(X, table, (const uint4*)d_ws, out);
}

// Round 11
// 213.386 us; speedup vs baseline: 1.0428x; 1.0428x over previous
//
#include <hip/hip_runtime.h>
#include <math.h>

typedef _Float16 half8  __attribute__((ext_vector_type(8)));
typedef float    float4v __attribute__((ext_vector_type(4)));

constexpr int T_ = 1 << 18;            // hash table size per level
constexpr unsigned TMASK = T_ - 1;
constexpr unsigned PRIME = 2654435761u;

// ws layout:
//   [0, 22528)      : 22 W-fragments (f16), frag f: 64 lanes x 8 halfs
//   [22528, 23360)  : biases fp32: b1[64] b2[64] b3[64] b4[16]
//   [23360, 23424)  : N_values fp32 [16]
//   [23424, 23488)  : level offsets fp32 [16] (prefix sum of N_l+1)
//   [23488, 57280)  : packed v1/v2 table, f16x2 pairs per entry
//   [57344, 57344+16MB) : f16-packed v3 table (if ws_size permits)
constexpr int WFRAG_HALFS = 22 * 64 * 8;   // 11264 halfs = 22528 B
constexpr int BIAS_FLOATS = 208;           // 3*64 + 16
constexpr int WS_BYTES    = 22528 + 240 * 4;   // 23488 (LDS-resident part)
constexpr int WS_UINT4    = WS_BYTES / 16;     // 1468
constexpr int V12_OFF     = 23488;
constexpr int V3T_OFF     = 57344;         // 64B-aligned start of f16 v3 table
constexpr size_t V3T_BYTES = (size_t)16 * T_ * 4;   // 16 MB

// R11: shrink the L2-miss fill stream. Model (R3-R10): dur == FETCH_lines /
// (8 XCD x ~1 line/cy) -- an MSHR-limited random-fill roofline. FETCH has been
// structure-invariant (174-178 MB) because it's determined by v3's access
// pattern: ~13.7 MB hot-line footprint thrashing 4 MB/XCD L2. Fix: f16-pack
// the v3 table (32->16 MB) at prep; footprint ~9 MB, 2x entries/line ->
// fewer miss lines per dispatch. v1/v2 have been f16 since R6 with absmax=0.
// Fallback to f32 table if ws_size < 16.1 MB (template<bool>, zero risk).
constexpr int BLK   = 256;                 // threads / block (4 waves)
constexpr int PTS_PER_BLOCK = 512;         // 4 waves x 8 tiles x 16 pts

struct Meta { float n[16]; float off[16]; };

// ---------------- prep: swizzle weights + pack v12 table ----------------
__global__ void prep_weights(const float* __restrict__ W1, const float* __restrict__ b1,
                             const float* __restrict__ W2, const float* __restrict__ b2,
                             const float* __restrict__ W3, const float* __restrict__ b3,
                             const float* __restrict__ W4, const float* __restrict__ b4,
                             const float2* __restrict__ table,
                             _Float16* __restrict__ wsW, float* __restrict__ wsB,
                             uint2* __restrict__ wsV, Meta mv)
{
    const int tid = threadIdx.x;
    const int bid = blockIdx.x;
    if (bid < 44) {
        const int e = bid * 256 + tid;              // 44*256 == WFRAG_HALFS exactly
        const int frag = e >> 9;
        const int l    = (e >> 3) & 63;
        const int j    = e & 7;
        const int g = l >> 4, m = l & 15;
        const int u = j >> 2, r = j & 3;            // k-pos split for sigma swizzle
        float v;
        if (frag < 4) {                       // L1: W1 (32x64), identity k-map
            v = W1[(8*g + j) * 64 + 16*frag + m];
        } else if (frag < 12) {               // L2: rows = sigma_s(8g+j) = 32s+16u+4g+r
            const int s = (frag - 4) >> 2, t = (frag - 4) & 3;
            v = W2[(32*s + 16*u + 4*g + r) * 64 + 16*t + m];
        } else if (frag < 20) {               // L3: ditto
            const int s = (frag - 12) >> 2, t = (frag - 12) & 3;
            v = W3[(32*s + 16*u + 4*g + r) * 64 + 16*t + m];
        } else {                              // L4 (64x3): ditto, pad n>=3 with 0
            const int s = frag - 20;
            v = (m < 3) ? W4[(32*s + 16*u + 4*g + r) * 3 + m] : 0.f;
        }
        wsW[e] = (_Float16)v;
    } else if (bid == 44) {
        if (tid < 64) { wsB[tid] = b1[tid]; wsB[64 + tid] = b2[tid]; wsB[128 + tid] = b3[tid]; }
        else if (tid < 80)  { const int r2 = tid - 64; wsB[192 + r2] = (r2 < 3) ? b4[r2] : 0.f; }
        else if (tid < 96)  wsB[BIAS_FLOATS + (tid - 80)] = mv.n[tid - 80];
        else if (tid < 112) wsB[BIAS_FLOATS + 16 + (tid - 96)] = mv.off[tid - 96];
    } else {
        // packed v12 table: entry e -> (level l, index i)
        const int e = (bid - 45) * 256 + tid;
        const int total = (int)mv.off[15] + (int)mv.n[15] + 1;   // 4194
        if (e < total) {
            int l = 0;
            #pragma unroll
            for (int k = 1; k < 16; ++k) if (e >= (int)mv.off[k]) l = k;
            const int i = e - (int)mv.off[l];
            const float2* tl = table + (size_t)l * T_;
            const float2 b = tl[((unsigned)i * PRIME) & TMASK];  // v1 source
            const float2 a = tl[i];                              // v2 source
            union { _Float16 h[2]; unsigned u; } p0, p1;
            p0.h[0] = (_Float16)b.x; p0.h[1] = (_Float16)b.y;
            p1.h[0] = (_Float16)a.x; p1.h[1] = (_Float16)a.y;
            wsV[e] = uint2{p0.u, p1.u};
        }
    }
}

// ---------------- prep: f16-pack the full v3 table (32 MB -> 16 MB) ----------------
__global__ void prep_table_f16(const float2* __restrict__ table, unsigned* __restrict__ t16)
{
    const size_t i = (size_t)blockIdx.x * 256 + threadIdx.x;   // 16384 blocks x 256
    const float2 v = table[i];                                 // grid == 16*T_ exactly
    union { _Float16 h[2]; unsigned u; } p;
    p.h[0] = (_Float16)v.x; p.h[1] = (_Float16)v.y;
    t16[i] = p.u;
}

// ---------------- main fused kernel ----------------
struct Gather {                // pipeline state (unused member DCE'd per template)
    float2   v3f[4];
    unsigned v3u[4];
    unsigned v1[4];
    unsigned v2[4];
};

template<bool F16T>
__device__ __forceinline__ void issue_gather(Gather& G, const float2 xy,
                                             const float2* __restrict__ table,
                                             const unsigned* __restrict__ t16,
                                             const unsigned* __restrict__ gV12,
                                             const float (&nvq)[4], const int (&offq)[4],
                                             const int g)
{
    #pragma unroll
    for (int q = 0; q < 4; ++q) {
        const float n = nvq[q];
        const float xs = xy.x * n, ys = xy.y * n;
        const int xi = (int)floorf(xs);
        const int yi = (int)floorf(ys);
        const unsigned yp = (unsigned)yi * PRIME;
        const size_t idx = (size_t)(4*g + q) * T_ + (((unsigned)xi ^ yp) & TMASK);
        if constexpr (F16T) G.v3u[q] = t16[idx];
        else                G.v3f[q] = table[idx];
        G.v1[q] = gV12[2*(offq[q] + yi) + 0];
        G.v2[q] = gV12[2*(offq[q] + xi) + 1];
    }
}

template<bool F16T>
__device__ __forceinline__ half8 make_feat(const float2 xy, const Gather& G,
                                           const float (&nvq)[4],
                                           const float2 (&v0c)[4])
{
    half8 feat;
    #pragma unroll
    for (int q = 0; q < 4; ++q) {
        const float n = nvq[q];
        const float xs = xy.x * n, ys = xy.y * n;
        const float xf = floorf(xs), yf = floorf(ys);
        const float fx = xs - xf, fy = ys - yf;
        union { unsigned u; _Float16 h[2]; } u1, u2, u3;
        u1.u = G.v1[q]; u2.u = G.v2[q];
        float v3x, v3y;
        if constexpr (F16T) { u3.u = G.v3u[q]; v3x = (float)u3.h[0]; v3y = (float)u3.h[1]; }
        else                { v3x = G.v3f[q].x; v3y = G.v3f[q].y; }
        const float cx = 1.f - fx, cy = 1.f - fy;
        const float w0 = cx*cy, w1 = cx*fy, w2 = fx*cy, w3 = fx*fy;
        feat[2*q+0] = (_Float16)(w0*v0c[q].x + w1*(float)u1.h[0] + w2*(float)u2.h[0] + w3*v3x);
        feat[2*q+1] = (_Float16)(w0*v0c[q].y + w1*(float)u1.h[1] + w2*(float)u2.h[1] + w3*v3y);
    }
    return feat;
}

// in-register layer handoff: leaky-relu + f16, a_s[4u+r] = f16(leaky(acc[2s+u][r]))
__device__ __forceinline__ void repack(const float4v (&acc)[4], half8& a0, half8& a1)
{
    #pragma unroll
    for (int u = 0; u < 2; ++u)
        #pragma unroll
        for (int r = 0; r < 4; ++r) {
            const float v0 = acc[u][r];
            const float v1 = acc[2 + u][r];
            a0[4*u + r] = (_Float16)(v0 > 0.f ? v0 : 0.01f * v0);
            a1[4*u + r] = (_Float16)(v1 > 0.f ? v1 : 0.01f * v1);
        }
}

template<bool F16T>
__global__ __launch_bounds__(BLK)
void fused_hashnerf_mfma(const float2* __restrict__ X,
                         const float2* __restrict__ table,
                         const uint4* __restrict__ ws,
                         float* __restrict__ out)
{
    __shared__ uint4 sRaw[WS_UINT4];           // W frags (f16) + biases + meta (23.5 KB)

    const int tid = threadIdx.x;
    for (int i = tid; i < WS_UINT4; i += BLK) sRaw[i] = ws[i];
    __syncthreads();

    const _Float16* Wl = (const _Float16*)sRaw;
    const float*    Bl = (const float*)(sRaw + (22528 / 16));
    const unsigned* gV12 = (const unsigned*)((const char*)ws + V12_OFF);
    const unsigned* t16  = (const unsigned*)((const char*)ws + V3T_OFF);

    const int wave = tid >> 6, lane = tid & 63;
    const int g = lane >> 4, c = lane & 15;

    // loop-invariant bias fragments: C'[n_out = 16t + 4g + r][pt]
    float4v b1f[4], b2f[4], b3f[4], b4f;
    #pragma unroll
    for (int t = 0; t < 4; ++t) {
        b1f[t] = *(const float4v*)(Bl +       16*t + 4*g);
        b2f[t] = *(const float4v*)(Bl +  64 + 16*t + 4*g);
        b3f[t] = *(const float4v*)(Bl + 128 + 16*t + 4*g);
    }
    b4f = *(const float4v*)(Bl + 192 + 4*g);
    float nvq[4];
    int   offq[4];
    #pragma unroll
    for (int q = 0; q < 4; ++q) {
        nvq[q]  = Bl[BIAS_FLOATS + 4*g + q];
        offq[q] = (int)Bl[BIAS_FLOATS + 16 + 4*g + q];
    }

    const int base_pt = blockIdx.x * PTS_PER_BLOCK + wave * 128;

    // X for all 8 tiles (coalesced/broadcast, static indices after unroll)
    float2 xy[8];
    #pragma unroll
    for (int it = 0; it < 8; ++it) xy[it] = X[base_pt + it*16 + c];

    // per-level constant corner (0,0): v0 = table[lv*T + 0] (f32, exact)
    float2 v0c[4];
    #pragma unroll
    for (int q = 0; q < 4; ++q) v0c[q] = table[(size_t)(4*g + q) * T_];

    // depth-2 gather pipeline: 3 rotating buffers, all indices static after unroll
    Gather G0, G1, G2;
    issue_gather<F16T>(G0, xy[0], table, t16, gV12, nvq, offq, g);
    issue_gather<F16T>(G1, xy[1], table, t16, gV12, nvq, offq, g);

    #pragma unroll
    for (int it = 0; it < 8; ++it) {
        Gather& Gc = (it % 3 == 0) ? G0 : (it % 3 == 1) ? G1 : G2;
        Gather& Gn = ((it + 2) % 3 == 0) ? G0 : ((it + 2) % 3 == 1) ? G1 : G2;

        // ---- consume tile it (vmcnt wait for its loads; newer stay in flight) ----
        const half8 feat = make_feat<F16T>(xy[it], Gc, nvq, v0c);

        // ---- issue tile it+2's gathers ----
        if (it < 6) issue_gather<F16T>(Gn, xy[it+2], table, t16, gV12, nvq, offq, g);
        __builtin_amdgcn_sched_barrier(0);

        // ---- L1: 4 independent MFMAs ----
        float4v acc[4];
        #pragma unroll
        for (int t = 0; t < 4; ++t) {
            const half8 wf = *(const half8*)(Wl + (t*64 + lane)*8);
            acc[t] = __builtin_amdgcn_mfma_f32_16x16x32_f16(wf, feat, b1f[t], 0, 0, 0);
        }

        // ---- L2 (in-register handoff, sigma-swizzled weights) ----
        half8 a0, a1;
        repack(acc, a0, a1);
        #pragma unroll
        for (int t = 0; t < 4; ++t) {
            const half8 w0f = *(const half8*)(Wl + ((4 + t)*64 + lane)*8);
            const half8 w1f = *(const half8*)(Wl + ((8 + t)*64 + lane)*8);
            float4v a = __builtin_amdgcn_mfma_f32_16x16x32_f16(w0f, a0, b2f[t], 0, 0, 0);
            acc[t]    = __builtin_amdgcn_mfma_f32_16x16x32_f16(w1f, a1, a,      0, 0, 0);
        }

        // ---- L3 ----
        repack(acc, a0, a1);
        #pragma unroll
        for (int t = 0; t < 4; ++t) {
            const half8 w0f = *(const half8*)(Wl + ((12 + t)*64 + lane)*8);
            const half8 w1f = *(const half8*)(Wl + ((16 + t)*64 + lane)*8);
            float4v a = __builtin_amdgcn_mfma_f32_16x16x32_f16(w0f, a0, b3f[t], 0, 0, 0);
            acc[t]    = __builtin_amdgcn_mfma_f32_16x16x32_f16(w1f, a1, a,      0, 0, 0);
        }

        // ---- L4: n_out = 0..2 live in lanes g==0 ----
        repack(acc, a0, a1);
        const half8 w40 = *(const half8*)(Wl + (20*64 + lane)*8);
        const half8 w41 = *(const half8*)(Wl + (21*64 + lane)*8);
        float4v o = __builtin_amdgcn_mfma_f32_16x16x32_f16(w40, a0, b4f, 0, 0, 0);
        o         = __builtin_amdgcn_mfma_f32_16x16x32_f16(w41, a1, o,   0, 0, 0);
        if (g == 0) {
            float* op = out + (size_t)3 * (base_pt + it * 16 + c);
            op[0] = fmaxf(o[0], 0.f);
            op[1] = fmaxf(o[1], 0.f);
            op[2] = fmaxf(o[2], 0.f);
        }
    }
}

extern "C" void kernel_launch(void* const* d_in, const int* in_sizes, int n_in,
                              void* d_out, int out_size, void* d_ws, size_t ws_size,
                              hipStream_t stream) {
    const float2* X     = (const float2*)d_in[0];
    const float2* table = (const float2*)d_in[1];
    const float*  W1    = (const float*)d_in[2];
    const float*  b1    = (const float*)d_in[3];
    const float*  W2    = (const float*)d_in[4];
    const float*  b2    = (const float*)d_in[5];
    const float*  W3    = (const float*)d_in[6];
    const float*  b3    = (const float*)d_in[7];
    const float*  W4    = (const float*)d_in[8];
    const float*  b4    = (const float*)d_in[9];
    float* out          = (float*)d_out;

    const int npts = in_sizes[0] / 2;

    Meta mv;
    const double bg = exp((log(1024.0) - log(16.0)) / 15.0);
    int acc = 0;
    for (int l = 0; l < 16; ++l) {
        const float nl = floorf((float)(16.0 * pow(bg, (double)l)));
        mv.n[l]   = nl;
        mv.off[l] = (float)acc;
        acc += (int)nl + 1;
    }

    _Float16* wsW = (_Float16*)d_ws;
    float*    wsB = (float*)((char*)d_ws + 22528);
    uint2*    wsV = (uint2*)((char*)d_ws + V12_OFF);
    unsigned* t16 = (unsigned*)((char*)d_ws + V3T_OFF);

    const bool f16t = ws_size >= (size_t)V3T_OFF + V3T_BYTES;

    prep_weights<<<62, 256, 0, stream>>>(W1, b1, W2, b2, W3, b3, W4, b4, table,
                                         wsW, wsB, wsV, mv);
    if (f16t) {
        prep_table_f16<<<16 * T_ / 256, 256, 0, stream>>>(table, t16);
        fused_hashnerf_mfma<true><<<npts / PTS_PER_BLOCK, BLK, 0, stream>>>(
            X, table, (const uint4*)d_ws, out);
    } else {
        fused_hashnerf_mfma<false><<<npts / PTS_PER_BLOCK, BLK, 0, stream>>>(
            X, table, (const uint4*)d_ws, out);
    }
}